// Round 3
// baseline (1367.419 us; speedup 1.0000x reference)
//
#include <hip/hip_runtime.h>
#include <hip/hip_bf16.h>

#define N_NODES  100000
#define N_EDGES  3200000
#define N_GRAPHS 1000
#define IN_DIM   10
#define HID      20
#define BN_EPS   1e-5f

#define BUCKET_SHIFT 8                       // 256 nodes per bucket
#define NB   ((N_NODES + 255) / 256)         // 391 buckets (== blocks for node kernels)
#define FILL_BLOCKS 512
#define CHUNK ((N_EDGES + FILL_BLOCKS - 1) / FILL_BLOCKS)   // 6250 edges/block

// ---------------------------------------------------------------------------
// Bucket histogram: per-block LDS hist, then one global add per bucket
// ---------------------------------------------------------------------------
__global__ __launch_bounds__(256) void hist_bucket(const int* __restrict__ dst,
                                                   int* __restrict__ gcnt) {
    __shared__ int cnt[NB];
    for (int i = threadIdx.x; i < NB; i += 256) cnt[i] = 0;
    __syncthreads();
    int e0 = blockIdx.x * CHUNK;
    int e1 = min(e0 + CHUNK, N_EDGES);
    for (int e = e0 + threadIdx.x; e < e1; e += 256)
        atomicAdd(&cnt[dst[e] >> BUCKET_SHIFT], 1);
    __syncthreads();
    for (int i = threadIdx.x; i < NB; i += 256)
        if (cnt[i]) atomicAdd(&gcnt[i], cnt[i]);
}

// ---------------------------------------------------------------------------
// Exclusive scan over NB buckets (single block); writes off[] and cursor[]
// ---------------------------------------------------------------------------
__global__ void scan_buckets(const int* __restrict__ gcnt,
                             int* __restrict__ off, int* __restrict__ cursor) {
    __shared__ int lds[512];
    int t = threadIdx.x;
    int v = (t < NB) ? gcnt[t] : 0;
    int val = v;
    lds[t] = val; __syncthreads();
    for (int o = 1; o < 512; o <<= 1) {
        int add = (t >= o) ? lds[t - o] : 0;
        __syncthreads();
        val += add; lds[t] = val;
        __syncthreads();
    }
    if (t < NB) { off[t] = val - v; cursor[t] = val - v; }
    if (t == 0) off[NB] = N_EDGES;
}

// ---------------------------------------------------------------------------
// Ranked fill: two passes over the block's chunk. Pass 1 counts per bucket in
// LDS; block reserves one contiguous range per bucket (atomic cursor); pass 2
// writes packed (src | ldst<<24) densely into the runs -> coalesced lines.
// ---------------------------------------------------------------------------
__global__ __launch_bounds__(256) void fill_bucket(const int* __restrict__ src,
                                                   const int* __restrict__ dst,
                                                   int* __restrict__ cursor,
                                                   unsigned* __restrict__ packed) {
    __shared__ int cnt[NB];
    __shared__ int base[NB];
    for (int i = threadIdx.x; i < NB; i += 256) cnt[i] = 0;
    __syncthreads();
    int e0 = blockIdx.x * CHUNK;
    int e1 = min(e0 + CHUNK, N_EDGES);
    for (int e = e0 + threadIdx.x; e < e1; e += 256)
        atomicAdd(&cnt[dst[e] >> BUCKET_SHIFT], 1);
    __syncthreads();
    for (int i = threadIdx.x; i < NB; i += 256) {
        int c = cnt[i];
        base[i] = c ? atomicAdd(&cursor[i], c) : 0;
        cnt[i] = 0;
    }
    __syncthreads();
    for (int e = e0 + threadIdx.x; e < e1; e += 256) {
        int d = dst[e];
        int b = d >> BUCKET_SHIFT;
        int lr = atomicAdd(&cnt[b], 1);
        packed[base[b] + lr] = (unsigned)src[e] | ((unsigned)(d & 255) << 24);
    }
}

// ---------------------------------------------------------------------------
// Fused per-bucket: LDS-accumulated gather + (h+agg)@W+b + BN-stat partials
// ---------------------------------------------------------------------------
template<int DIN>
__global__ __launch_bounds__(256) void gather_mlp_bucket(
        const float* __restrict__ h,
        const int* __restrict__ off, const unsigned* __restrict__ packed,
        const float* __restrict__ W,   // [DIN][HID]
        const float* __restrict__ bias,
        float* __restrict__ hpre,      // [N][HID]
        float* __restrict__ partials)  // [NB][2*HID]
{
    constexpr int PAD = DIN + 1;       // odd stride -> conflict-free tail reads
    __shared__ float acc[256 * PAD];
    __shared__ float red[4][2 * HID];
    int t = threadIdx.x;
    int bb = blockIdx.x;
    int n = bb * 256 + t;

    // self term init
    if (n < N_NODES) {
        if constexpr (DIN == 20) {
            const float4* hv = (const float4*)(h + (size_t)n * DIN);
#pragma unroll
            for (int q = 0; q < 5; q++) {
                float4 a = hv[q];
                acc[t * PAD + 4 * q + 0] = a.x;
                acc[t * PAD + 4 * q + 1] = a.y;
                acc[t * PAD + 4 * q + 2] = a.z;
                acc[t * PAD + 4 * q + 3] = a.w;
            }
        } else {
            const float2* hv = (const float2*)(h + (size_t)n * DIN);
#pragma unroll
            for (int q = 0; q < 5; q++) {
                float2 a = hv[q];
                acc[t * PAD + 2 * q + 0] = a.x;
                acc[t * PAD + 2 * q + 1] = a.y;
            }
        }
    }
    __syncthreads();

    // edge accumulation into LDS
    int e0 = off[bb], e1 = off[bb + 1];
    for (int e = e0 + t; e < e1; e += 256) {
        unsigned p = packed[e];
        int s = p & 0xFFFFFF;
        int l = p >> 24;
        if constexpr (DIN == 20) {
            const float4* sv = (const float4*)(h + (size_t)s * DIN);
#pragma unroll
            for (int q = 0; q < 5; q++) {
                float4 a = sv[q];
                atomicAdd(&acc[l * PAD + 4 * q + 0], a.x);
                atomicAdd(&acc[l * PAD + 4 * q + 1], a.y);
                atomicAdd(&acc[l * PAD + 4 * q + 2], a.z);
                atomicAdd(&acc[l * PAD + 4 * q + 3], a.w);
            }
        } else {
            const float2* sv = (const float2*)(h + (size_t)s * DIN);
#pragma unroll
            for (int q = 0; q < 5; q++) {
                float2 a = sv[q];
                atomicAdd(&acc[l * PAD + 2 * q + 0], a.x);
                atomicAdd(&acc[l * PAD + 2 * q + 1], a.y);
            }
        }
    }
    __syncthreads();

    // MLP tail
    float out[HID];
    if (n < N_NODES) {
#pragma unroll
        for (int j = 0; j < HID; j++) out[j] = bias[j];
#pragma unroll
        for (int k = 0; k < DIN; k++) {
            float u = acc[t * PAD + k];
#pragma unroll
            for (int j = 0; j < HID; j++)
                out[j] = fmaf(u, W[k * HID + j], out[j]);
        }
        float4* ov = (float4*)(hpre + (size_t)n * HID);
#pragma unroll
        for (int q = 0; q < 5; q++) {
            float4 a;
            a.x = out[4*q]; a.y = out[4*q+1]; a.z = out[4*q+2]; a.w = out[4*q+3];
            ov[q] = a;
        }
    } else {
#pragma unroll
        for (int j = 0; j < HID; j++) out[j] = 0.0f;
    }

    // BN partials: wave shuffle -> cross-wave LDS -> per-block row
    int lane = t & 63;
    int wave = t >> 6;
#pragma unroll
    for (int j = 0; j < HID; j++) {
        float s1 = out[j];
        float s2 = s1 * s1;
        for (int o = 32; o; o >>= 1) {
            s1 += __shfl_down(s1, o);
            s2 += __shfl_down(s2, o);
        }
        if (lane == 0) { red[wave][j] = s1; red[wave][HID + j] = s2; }
    }
    __syncthreads();
    if (t < 2 * HID) {
        float s = red[0][t] + red[1][t] + red[2][t] + red[3][t];
        partials[bb * (2 * HID) + t] = s;
    }
}

// ---------------------------------------------------------------------------
// Reduce partials (f64) -> per-channel scale/shift
// ---------------------------------------------------------------------------
__global__ void bn_prep_kernel(const float* __restrict__ partials,
                               const float* __restrict__ g,
                               const float* __restrict__ beta,
                               float* __restrict__ ss) {
    __shared__ double sums[2 * HID];
    int t = threadIdx.x;
    if (t < 2 * HID) {
        double a = 0.0;
        for (int bidx = 0; bidx < NB; bidx++)
            a += (double)partials[bidx * (2 * HID) + t];
        sums[t] = a;
    }
    __syncthreads();
    if (t < HID) {
        double mu  = sums[t] / (double)N_NODES;
        double var = sums[HID + t] / (double)N_NODES - mu * mu;
        float sc = g[t] * (float)(1.0 / sqrt(var + (double)BN_EPS));
        ss[t]       = sc;
        ss[HID + t] = beta[t] - (float)mu * sc;
    }
}

// ---------------------------------------------------------------------------
// BN apply + ReLU, float4
// ---------------------------------------------------------------------------
__global__ void bn_relu_kernel(const float4* __restrict__ hpre4,
                               const float* __restrict__ ss,
                               float4* __restrict__ hout4) {
    __shared__ float s_ss[2 * HID];
    if (threadIdx.x < 2 * HID) s_ss[threadIdx.x] = ss[threadIdx.x];
    __syncthreads();
    int i = blockIdx.x * blockDim.x + threadIdx.x;
    if (i < N_NODES * HID / 4) {
        int c0 = (i % 5) * 4;
        float4 v = hpre4[i];
        v.x = fmaf(v.x, s_ss[c0 + 0], s_ss[HID + c0 + 0]); v.x = v.x > 0.f ? v.x : 0.f;
        v.y = fmaf(v.y, s_ss[c0 + 1], s_ss[HID + c0 + 1]); v.y = v.y > 0.f ? v.y : 0.f;
        v.z = fmaf(v.z, s_ss[c0 + 2], s_ss[HID + c0 + 2]); v.z = v.z > 0.f ? v.z : 0.f;
        v.w = fmaf(v.w, s_ss[c0 + 3], s_ss[HID + c0 + 3]); v.w = v.w > 0.f ? v.w : 0.f;
        hout4[i] = v;
    }
}

// ---------------------------------------------------------------------------
// graph_ptr from sorted batch (handles empty graphs)
// ---------------------------------------------------------------------------
__global__ void gptr_kernel(const int* __restrict__ batch, int* __restrict__ gptr) {
    int n = blockIdx.x * blockDim.x + threadIdx.x;
    if (n >= N_NODES) return;
    int g = batch[n];
    int gp = (n == 0) ? -1 : batch[n - 1];
    for (int q = gp + 1; q <= g; q++) gptr[q] = n;
    if (n == N_NODES - 1)
        for (int q = g + 1; q <= N_GRAPHS; q++) gptr[q] = N_NODES;
}

// ---------------------------------------------------------------------------
// Pool: block per graph, coalesced lane-contiguous reads, LDS reduce
// ---------------------------------------------------------------------------
__global__ __launch_bounds__(256) void pool_kernel(const float* __restrict__ h,
                                                   const int* __restrict__ gptr,
                                                   float* __restrict__ pooled) {
    __shared__ float red[12][HID];
    int g = blockIdx.x;
    int n0 = gptr[g], n1 = gptr[g + 1];
    int t = threadIdx.x;
    if (t < 240) {
        int c = t % HID, grp = t / HID;           // 12 groups of 20
        float s = 0.0f;
        for (int n = n0 + grp; n < n1; n += 12)
            s += h[(size_t)n * HID + c];
        red[grp][c] = s;
    }
    __syncthreads();
    if (t < HID) {
        float a = 0.0f;
#pragma unroll
        for (int q = 0; q < 12; q++) a += red[q][t];
        pooled[g * HID + t] = a;
    }
}

// ---------------------------------------------------------------------------
// Final FC: [1000,20] @ [20,2] + b
// ---------------------------------------------------------------------------
__global__ void fc_kernel(const float* __restrict__ pooled,
                          const float* __restrict__ fcW,
                          const float* __restrict__ fcb,
                          float* __restrict__ out) {
    int gidx = blockIdx.x * blockDim.x + threadIdx.x;
    if (gidx < N_GRAPHS) {
        float o0 = fcb[0], o1 = fcb[1];
#pragma unroll
        for (int k = 0; k < HID; k++) {
            float p = pooled[gidx * HID + k];
            o0 = fmaf(p, fcW[k * 2 + 0], o0);
            o1 = fmaf(p, fcW[k * 2 + 1], o1);
        }
        out[gidx * 2 + 0] = o0;
        out[gidx * 2 + 1] = o1;
    }
}

extern "C" void kernel_launch(void* const* d_in, const int* in_sizes, int n_in,
                              void* d_out, int out_size, void* d_ws, size_t ws_size,
                              hipStream_t stream) {
    const float* x     = (const float*)d_in[0];
    const int*   eidx  = (const int*)d_in[1];
    const int*   batch = (const int*)d_in[2];
    const float* W1 = (const float*)d_in[3];
    const float* b1 = (const float*)d_in[4];
    const float* g1 = (const float*)d_in[5];
    const float* be1 = (const float*)d_in[6];
    const float* W2 = (const float*)d_in[7];
    const float* b2 = (const float*)d_in[8];
    const float* g2 = (const float*)d_in[9];
    const float* be2 = (const float*)d_in[10];
    const float* W3 = (const float*)d_in[11];
    const float* b3 = (const float*)d_in[12];
    const float* g3 = (const float*)d_in[13];
    const float* be3 = (const float*)d_in[14];
    const float* fcW = (const float*)d_in[15];
    const float* fcb = (const float*)d_in[16];
    float* out = (float*)d_out;

    const int* src = eidx;
    const int* dst = eidx + N_EDGES;

    // workspace layout (bytes)
    char* ws = (char*)d_ws;
    unsigned* packed = (unsigned*)(ws + 0);          // 12,800,000
    int*   off     = (int*)(ws + 12800000);          // (NB+1)*4 = 1568
    int*   cursor  = (int*)(ws + 12802000);          // 1564
    int*   gcnt    = (int*)(ws + 12804000);          // 1564
    float* hpre    = (float*)(ws + 12806400);        // 8,000,000 (16B aligned)
    float* hcur    = (float*)(ws + 20806400);        // 8,000,000 (16B aligned)
    float* partials= (float*)(ws + 28806400);        // NB*40*4 = 62,560
    float* ss      = (float*)(ws + 28869120);        // 160
    int*   gptr    = (int*)(ws + 28870000);          // 4,004
    float* pooled  = (float*)(ws + 28876000);        // 80,000

    const int BLK = 256;
    const int elem4_blocks = (N_NODES * HID / 4 + BLK - 1) / BLK;

    // ---- bucket-sorted edge list (built once, reused by all 3 layers) ----
    hipMemsetAsync(gcnt, 0, NB * sizeof(int), stream);
    hist_bucket<<<FILL_BLOCKS, BLK, 0, stream>>>(dst, gcnt);
    scan_buckets<<<1, 512, 0, stream>>>(gcnt, off, cursor);
    fill_bucket<<<FILL_BLOCKS, BLK, 0, stream>>>(src, dst, cursor, packed);

    // ---- layer 1 (DIN=10) ----
    gather_mlp_bucket<IN_DIM><<<NB, BLK, 0, stream>>>(x, off, packed, W1, b1, hpre, partials);
    bn_prep_kernel<<<1, 64, 0, stream>>>(partials, g1, be1, ss);
    bn_relu_kernel<<<elem4_blocks, BLK, 0, stream>>>((const float4*)hpre, ss, (float4*)hcur);

    // ---- layer 2 (DIN=20) ----
    gather_mlp_bucket<HID><<<NB, BLK, 0, stream>>>(hcur, off, packed, W2, b2, hpre, partials);
    bn_prep_kernel<<<1, 64, 0, stream>>>(partials, g2, be2, ss);
    bn_relu_kernel<<<elem4_blocks, BLK, 0, stream>>>(hpre ? (const float4*)hpre : nullptr, ss, (float4*)hcur);

    // ---- layer 3 (DIN=20) ----
    gather_mlp_bucket<HID><<<NB, BLK, 0, stream>>>(hcur, off, packed, W3, b3, hpre, partials);
    bn_prep_kernel<<<1, 64, 0, stream>>>(partials, g3, be3, ss);
    bn_relu_kernel<<<elem4_blocks, BLK, 0, stream>>>((const float4*)hpre, ss, (float4*)hcur);

    // ---- pool + FC ----
    gptr_kernel<<<NB, BLK, 0, stream>>>(batch, gptr);
    pool_kernel<<<N_GRAPHS, BLK, 0, stream>>>(hcur, gptr, pooled);
    fc_kernel<<<(N_GRAPHS + BLK - 1) / BLK, BLK, 0, stream>>>(pooled, fcW, fcb, out);
}

// Round 4
// 542.335 us; speedup vs baseline: 2.5214x; 2.5214x over previous
//
#include <hip/hip_runtime.h>
#include <hip/hip_bf16.h>

#define N_NODES  100000
#define N_EDGES  3200000
#define N_GRAPHS 1000
#define IN_DIM   10
#define HID      20
#define BN_EPS   1e-5f

#define NB   ((N_NODES + 255) / 256)         // 391 buckets of 256 nodes
#define FILL_BLOCKS 512
#define CHUNK ((N_EDGES + FILL_BLOCKS - 1) / FILL_BLOCKS)   // 6250 edges/block
#define MAXB 12288                            // per-bucket LDS sort capacity (48 KB)
#define NBG  ((N_NODES + 63) / 64)            // 1563 gather blocks (64 nodes each)

// ---------------------------------------------------------------------------
// Bucket histogram: per-block LDS hist, then one global add per bucket
// ---------------------------------------------------------------------------
__global__ __launch_bounds__(256) void hist_bucket(const int* __restrict__ dst,
                                                   int* __restrict__ gcnt) {
    __shared__ int cnt[NB];
    for (int i = threadIdx.x; i < NB; i += 256) cnt[i] = 0;
    __syncthreads();
    int e0 = blockIdx.x * CHUNK;
    int e1 = min(e0 + CHUNK, N_EDGES);
    for (int e = e0 + threadIdx.x; e < e1; e += 256)
        atomicAdd(&cnt[dst[e] >> 8], 1);
    __syncthreads();
    for (int i = threadIdx.x; i < NB; i += 256)
        if (cnt[i]) atomicAdd(&gcnt[i], cnt[i]);
}

// ---------------------------------------------------------------------------
// Exclusive scan over NB buckets (single block)
// ---------------------------------------------------------------------------
__global__ void scan_buckets(const int* __restrict__ gcnt,
                             int* __restrict__ off, int* __restrict__ cursor) {
    __shared__ int lds[512];
    int t = threadIdx.x;
    int v = (t < NB) ? gcnt[t] : 0;
    int val = v;
    lds[t] = val; __syncthreads();
    for (int o = 1; o < 512; o <<= 1) {
        int add = (t >= o) ? lds[t - o] : 0;
        __syncthreads();
        val += add; lds[t] = val;
        __syncthreads();
    }
    if (t < NB) { off[t] = val - v; cursor[t] = val - v; }
    if (t == 0) off[NB] = N_EDGES;
}

// ---------------------------------------------------------------------------
// Ranked fill into bucket-contiguous runs; packed = src | (dst&255)<<24
// ---------------------------------------------------------------------------
__global__ __launch_bounds__(256) void fill_bucket(const int* __restrict__ src,
                                                   const int* __restrict__ dst,
                                                   int* __restrict__ cursor,
                                                   unsigned* __restrict__ packed) {
    __shared__ int cnt[NB];
    __shared__ int base[NB];
    for (int i = threadIdx.x; i < NB; i += 256) cnt[i] = 0;
    __syncthreads();
    int e0 = blockIdx.x * CHUNK;
    int e1 = min(e0 + CHUNK, N_EDGES);
    for (int e = e0 + threadIdx.x; e < e1; e += 256)
        atomicAdd(&cnt[dst[e] >> 8], 1);
    __syncthreads();
    for (int i = threadIdx.x; i < NB; i += 256) {
        int c = cnt[i];
        base[i] = c ? atomicAdd(&cursor[i], c) : 0;
        cnt[i] = 0;
    }
    __syncthreads();
    for (int e = e0 + threadIdx.x; e < e1; e += 256) {
        int d = dst[e];
        int b = d >> 8;
        int lr = atomicAdd(&cnt[b], 1);
        packed[base[b] + lr] = (unsigned)src[e] | ((unsigned)(d & 255) << 24);
    }
}

// ---------------------------------------------------------------------------
// Per-bucket counting sort by local dst -> node-exact CSR (csr, rp)
// ---------------------------------------------------------------------------
__global__ __launch_bounds__(256) void sort_bucket(const unsigned* __restrict__ packed,
                                                   const int* __restrict__ off,
                                                   int* __restrict__ csr,
                                                   int* __restrict__ rp) {
    __shared__ unsigned ebuf[MAXB];
    __shared__ int cnt[256];
    __shared__ int cur[256];
    int b = blockIdx.x, t = threadIdx.x;
    int e0 = off[b], e1 = off[b + 1], m = e1 - e0;
    bool inlds = (m <= MAXB);
    if (inlds)
        for (int i = t; i < m; i += 256) ebuf[i] = packed[e0 + i];
    cnt[t] = 0;
    __syncthreads();
    for (int i = t; i < m; i += 256) {
        unsigned p = inlds ? ebuf[i] : packed[e0 + i];
        atomicAdd(&cnt[p >> 24], 1);
    }
    __syncthreads();
    // exclusive scan of cnt[256]
    int v = cnt[t];
    int val = v;
    cur[t] = val; __syncthreads();
    for (int o = 1; o < 256; o <<= 1) {
        int add = (t >= o) ? cur[t - o] : 0;
        __syncthreads();
        val += add; cur[t] = val;
        __syncthreads();
    }
    int excl = val - v;
    int node = b * 256 + t;
    if (node <= N_NODES) rp[node] = e0 + excl;   // last bucket also writes rp[N]
    cur[t] = excl;
    __syncthreads();
    for (int i = t; i < m; i += 256) {
        unsigned p = inlds ? ebuf[i] : packed[e0 + i];
        int l = p >> 24;
        int pos = atomicAdd(&cur[l], 1);
        csr[e0 + pos] = (int)(p & 0xFFFFFFu);
    }
}

// ---------------------------------------------------------------------------
// Gather + MLP + BN partials. 4 threads per node, register accumulation,
// butterfly merge, each sub-thread computes 5 of the 20 outputs.
// ---------------------------------------------------------------------------
template<int DIN>
__global__ __launch_bounds__(256) void gather_mlp4(
        const float* __restrict__ h,
        const int* __restrict__ rp, const int* __restrict__ csr,
        const float* __restrict__ W,    // [DIN][HID]
        const float* __restrict__ bias,
        float* __restrict__ hpre,       // [N][HID]
        float* __restrict__ partials)   // [NBG][2*HID]
{
    __shared__ float sW[DIN * HID];
    __shared__ float sb[HID];
    __shared__ float red[4][2 * HID];
    int t = threadIdx.x;
    for (int i = t; i < DIN * HID; i += 256) sW[i] = W[i];
    if (t < HID) sb[t] = bias[t];
    __syncthreads();

    int node = blockIdx.x * 64 + (t >> 2);
    int sub  = t & 3;
    float u[DIN];
#pragma unroll
    for (int k = 0; k < DIN; k++) u[k] = 0.0f;

    if (node < N_NODES) {
        if (sub == 0) {  // self term
            if constexpr (DIN == 20) {
                const float4* hv = (const float4*)(h + (size_t)node * DIN);
#pragma unroll
                for (int q = 0; q < 5; q++) {
                    float4 a = hv[q];
                    u[4*q] = a.x; u[4*q+1] = a.y; u[4*q+2] = a.z; u[4*q+3] = a.w;
                }
            } else {
                const float2* hv = (const float2*)(h + (size_t)node * DIN);
#pragma unroll
                for (int q = 0; q < 5; q++) {
                    float2 a = hv[q];
                    u[2*q] = a.x; u[2*q+1] = a.y;
                }
            }
        }
        int e0 = rp[node], e1 = rp[node + 1];
        int e = e0 + sub;
        // 2-edge unrolled: more loads in flight
        for (; e + 4 < e1; e += 8) {
            int s0 = csr[e], s1 = csr[e + 4];
            if constexpr (DIN == 20) {
                const float4* a0 = (const float4*)(h + (size_t)s0 * DIN);
                const float4* a1 = (const float4*)(h + (size_t)s1 * DIN);
#pragma unroll
                for (int q = 0; q < 5; q++) {
                    float4 x0 = a0[q], x1 = a1[q];
                    u[4*q]   += x0.x + x1.x;
                    u[4*q+1] += x0.y + x1.y;
                    u[4*q+2] += x0.z + x1.z;
                    u[4*q+3] += x0.w + x1.w;
                }
            } else {
                const float2* a0 = (const float2*)(h + (size_t)s0 * DIN);
                const float2* a1 = (const float2*)(h + (size_t)s1 * DIN);
#pragma unroll
                for (int q = 0; q < 5; q++) {
                    float2 x0 = a0[q], x1 = a1[q];
                    u[2*q]   += x0.x + x1.x;
                    u[2*q+1] += x0.y + x1.y;
                }
            }
        }
        if (e < e1) {
            int s0 = csr[e];
            if constexpr (DIN == 20) {
                const float4* a0 = (const float4*)(h + (size_t)s0 * DIN);
#pragma unroll
                for (int q = 0; q < 5; q++) {
                    float4 x0 = a0[q];
                    u[4*q] += x0.x; u[4*q+1] += x0.y; u[4*q+2] += x0.z; u[4*q+3] += x0.w;
                }
            } else {
                const float2* a0 = (const float2*)(h + (size_t)s0 * DIN);
#pragma unroll
                for (int q = 0; q < 5; q++) {
                    float2 x0 = a0[q];
                    u[2*q] += x0.x; u[2*q+1] += x0.y;
                }
            }
        }
    }

    // merge the 4 sub-accumulators (all 4 lanes end with the full sum)
#pragma unroll
    for (int k = 0; k < DIN; k++) {
        u[k] += __shfl_xor(u[k], 1);
        u[k] += __shfl_xor(u[k], 2);
    }

    // MLP: this sub-thread computes channels [sub*5, sub*5+5)
    const int c0 = sub * 5;
    float out[5];
#pragma unroll
    for (int j = 0; j < 5; j++) out[j] = sb[c0 + j];
#pragma unroll
    for (int k = 0; k < DIN; k++) {
        float uk = u[k];
#pragma unroll
        for (int j = 0; j < 5; j++)
            out[j] = fmaf(uk, sW[k * HID + c0 + j], out[j]);
    }
    if (node < N_NODES) {
        float* op = hpre + (size_t)node * HID + c0;
#pragma unroll
        for (int j = 0; j < 5; j++) op[j] = out[j];
    } else {
#pragma unroll
        for (int j = 0; j < 5; j++) out[j] = 0.0f;
    }

    // BN partials: reduce across the 16 nodes of each wave (same sub), then LDS
    float s1[5], s2[5];
#pragma unroll
    for (int j = 0; j < 5; j++) { s1[j] = out[j]; s2[j] = out[j] * out[j]; }
    for (int o = 4; o < 64; o <<= 1) {
#pragma unroll
        for (int j = 0; j < 5; j++) {
            s1[j] += __shfl_down(s1[j], o);
            s2[j] += __shfl_down(s2[j], o);
        }
    }
    int lane = t & 63, wave = t >> 6;
    if (lane < 4) {
#pragma unroll
        for (int j = 0; j < 5; j++) {
            red[wave][lane * 5 + j]       = s1[j];
            red[wave][HID + lane * 5 + j] = s2[j];
        }
    }
    __syncthreads();
    if (t < 2 * HID)
        partials[blockIdx.x * (2 * HID) + t] =
            red[0][t] + red[1][t] + red[2][t] + red[3][t];
}

// ---------------------------------------------------------------------------
// Reduce partials (f64) -> per-channel scale/shift. 320 thr = 40 ch x 8 slices
// ---------------------------------------------------------------------------
__global__ void bn_prep_kernel(const float* __restrict__ partials,
                               const float* __restrict__ g,
                               const float* __restrict__ beta,
                               float* __restrict__ ss) {
    __shared__ double acc[8][2 * HID];
    int t = threadIdx.x;             // 320
    int c = t % (2 * HID), s = t / (2 * HID);
    double a = 0.0;
    for (int r = s; r < NBG; r += 8)
        a += (double)partials[r * (2 * HID) + c];
    acc[s][c] = a;
    __syncthreads();
    if (t < HID) {
        double su = 0.0, sq = 0.0;
#pragma unroll
        for (int q = 0; q < 8; q++) { su += acc[q][t]; sq += acc[q][HID + t]; }
        double mu  = su / (double)N_NODES;
        double var = sq / (double)N_NODES - mu * mu;
        float sc = g[t] * (float)(1.0 / sqrt(var + (double)BN_EPS));
        ss[t]       = sc;
        ss[HID + t] = beta[t] - (float)mu * sc;
    }
}

// ---------------------------------------------------------------------------
// BN apply + ReLU, float4
// ---------------------------------------------------------------------------
__global__ void bn_relu_kernel(const float4* __restrict__ hpre4,
                               const float* __restrict__ ss,
                               float4* __restrict__ hout4) {
    __shared__ float s_ss[2 * HID];
    if (threadIdx.x < 2 * HID) s_ss[threadIdx.x] = ss[threadIdx.x];
    __syncthreads();
    int i = blockIdx.x * blockDim.x + threadIdx.x;
    if (i < N_NODES * HID / 4) {
        int c0 = (i % 5) * 4;
        float4 v = hpre4[i];
        v.x = fmaf(v.x, s_ss[c0 + 0], s_ss[HID + c0 + 0]); v.x = v.x > 0.f ? v.x : 0.f;
        v.y = fmaf(v.y, s_ss[c0 + 1], s_ss[HID + c0 + 1]); v.y = v.y > 0.f ? v.y : 0.f;
        v.z = fmaf(v.z, s_ss[c0 + 2], s_ss[HID + c0 + 2]); v.z = v.z > 0.f ? v.z : 0.f;
        v.w = fmaf(v.w, s_ss[c0 + 3], s_ss[HID + c0 + 3]); v.w = v.w > 0.f ? v.w : 0.f;
        hout4[i] = v;
    }
}

// ---------------------------------------------------------------------------
// graph_ptr from sorted batch (handles empty graphs)
// ---------------------------------------------------------------------------
__global__ void gptr_kernel(const int* __restrict__ batch, int* __restrict__ gptr) {
    int n = blockIdx.x * blockDim.x + threadIdx.x;
    if (n >= N_NODES) return;
    int g = batch[n];
    int gp = (n == 0) ? -1 : batch[n - 1];
    for (int q = gp + 1; q <= g; q++) gptr[q] = n;
    if (n == N_NODES - 1)
        for (int q = g + 1; q <= N_GRAPHS; q++) gptr[q] = N_NODES;
}

// ---------------------------------------------------------------------------
// Pool: block per graph, coalesced lane-contiguous reads, LDS reduce
// ---------------------------------------------------------------------------
__global__ __launch_bounds__(256) void pool_kernel(const float* __restrict__ h,
                                                   const int* __restrict__ gptr,
                                                   float* __restrict__ pooled) {
    __shared__ float red[12][HID];
    int g = blockIdx.x;
    int n0 = gptr[g], n1 = gptr[g + 1];
    int t = threadIdx.x;
    if (t < 240) {
        int c = t % HID, grp = t / HID;
        float s = 0.0f;
        for (int n = n0 + grp; n < n1; n += 12)
            s += h[(size_t)n * HID + c];
        red[grp][c] = s;
    }
    __syncthreads();
    if (t < HID) {
        float a = 0.0f;
#pragma unroll
        for (int q = 0; q < 12; q++) a += red[q][t];
        pooled[g * HID + t] = a;
    }
}

// ---------------------------------------------------------------------------
// Final FC: [1000,20] @ [20,2] + b
// ---------------------------------------------------------------------------
__global__ void fc_kernel(const float* __restrict__ pooled,
                          const float* __restrict__ fcW,
                          const float* __restrict__ fcb,
                          float* __restrict__ out) {
    int gidx = blockIdx.x * blockDim.x + threadIdx.x;
    if (gidx < N_GRAPHS) {
        float o0 = fcb[0], o1 = fcb[1];
#pragma unroll
        for (int k = 0; k < HID; k++) {
            float p = pooled[gidx * HID + k];
            o0 = fmaf(p, fcW[k * 2 + 0], o0);
            o1 = fmaf(p, fcW[k * 2 + 1], o1);
        }
        out[gidx * 2 + 0] = o0;
        out[gidx * 2 + 1] = o1;
    }
}

extern "C" void kernel_launch(void* const* d_in, const int* in_sizes, int n_in,
                              void* d_out, int out_size, void* d_ws, size_t ws_size,
                              hipStream_t stream) {
    const float* x     = (const float*)d_in[0];
    const int*   eidx  = (const int*)d_in[1];
    const int*   batch = (const int*)d_in[2];
    const float* W1 = (const float*)d_in[3];
    const float* b1 = (const float*)d_in[4];
    const float* g1 = (const float*)d_in[5];
    const float* be1 = (const float*)d_in[6];
    const float* W2 = (const float*)d_in[7];
    const float* b2 = (const float*)d_in[8];
    const float* g2 = (const float*)d_in[9];
    const float* be2 = (const float*)d_in[10];
    const float* W3 = (const float*)d_in[11];
    const float* b3 = (const float*)d_in[12];
    const float* g3 = (const float*)d_in[13];
    const float* be3 = (const float*)d_in[14];
    const float* fcW = (const float*)d_in[15];
    const float* fcb = (const float*)d_in[16];
    float* out = (float*)d_out;

    const int* src = eidx;
    const int* dst = eidx + N_EDGES;

    // workspace layout (bytes).  packed (build-only) ALIASES hpre/hcur:
    // build phase (hist/scan/fill/sort) completes before hpre/hcur are written.
    char* ws = (char*)d_ws;
    unsigned* packed = (unsigned*)(ws + 0);          // 12,800,000 (temp)
    float* hpre    = (float*)(ws + 0);               // 8,000,000
    float* hcur    = (float*)(ws + 8000000);         // 8,000,000
    int*   csr     = (int*)(ws + 16000000);          // 12,800,000
    int*   rp      = (int*)(ws + 28800000);          // 400,004
    int*   off     = (int*)(ws + 29200128);          // 1,568
    int*   cursor  = (int*)(ws + 29201792);          // 1,564
    int*   gcnt    = (int*)(ws + 29203456);          // 1,564
    float* partials= (float*)(ws + 29205120);        // NBG*40*4 = 250,080
    float* ss      = (float*)(ws + 29455360);        // 160
    int*   gptr    = (int*)(ws + 29455616);          // 4,004
    float* pooled  = (float*)(ws + 29459712);        // 80,000

    const int BLK = 256;
    const int elem4_blocks = (N_NODES * HID / 4 + BLK - 1) / BLK;

    // ---- sorted node-exact CSR (built once, reused by all 3 layers) ----
    hipMemsetAsync(gcnt, 0, NB * sizeof(int), stream);
    hist_bucket<<<FILL_BLOCKS, BLK, 0, stream>>>(dst, gcnt);
    scan_buckets<<<1, 512, 0, stream>>>(gcnt, off, cursor);
    fill_bucket<<<FILL_BLOCKS, BLK, 0, stream>>>(src, dst, cursor, packed);
    sort_bucket<<<NB, BLK, 0, stream>>>(packed, off, csr, rp);

    // ---- layer 1 (DIN=10) ----
    gather_mlp4<IN_DIM><<<NBG, BLK, 0, stream>>>(x, rp, csr, W1, b1, hpre, partials);
    bn_prep_kernel<<<1, 320, 0, stream>>>(partials, g1, be1, ss);
    bn_relu_kernel<<<elem4_blocks, BLK, 0, stream>>>((const float4*)hpre, ss, (float4*)hcur);

    // ---- layer 2 (DIN=20) ----
    gather_mlp4<HID><<<NBG, BLK, 0, stream>>>(hcur, rp, csr, W2, b2, hpre, partials);
    bn_prep_kernel<<<1, 320, 0, stream>>>(partials, g2, be2, ss);
    bn_relu_kernel<<<elem4_blocks, BLK, 0, stream>>>((const float4*)hpre, ss, (float4*)hcur);

    // ---- layer 3 (DIN=20) ----
    gather_mlp4<HID><<<NBG, BLK, 0, stream>>>(hcur, rp, csr, W3, b3, hpre, partials);
    bn_prep_kernel<<<1, 320, 0, stream>>>(partials, g3, be3, ss);
    bn_relu_kernel<<<elem4_blocks, BLK, 0, stream>>>((const float4*)hpre, ss, (float4*)hcur);

    // ---- pool + FC ----
    gptr_kernel<<<NB, BLK, 0, stream>>>(batch, gptr);
    pool_kernel<<<N_GRAPHS, BLK, 0, stream>>>(hcur, gptr, pooled);
    fc_kernel<<<(N_GRAPHS + BLK - 1) / BLK, BLK, 0, stream>>>(pooled, fcW, fcb, out);
}

// Round 5
// 366.851 us; speedup vs baseline: 3.7275x; 1.4784x over previous
//
#include <hip/hip_runtime.h>
#include <hip/hip_bf16.h>

#define N_NODES  100000
#define N_EDGES  3200000
#define N_GRAPHS 1000
#define IN_DIM   10
#define HID      20
#define BN_EPS   1e-5f

#define BSH   7                              // 128-node buckets
#define NB    ((N_NODES + 127) / 128)        // 782 buckets
#define FILL_BLOCKS 512
#define CHUNK ((N_EDGES + FILL_BLOCKS - 1) / FILL_BLOCKS)   // 6250 edges/block
#define MAXB  6144                           // per-bucket LDS sort capacity (24 KB)
#define NBG   ((N_NODES + 31) / 32)          // 3125 gather blocks (32 nodes, 8 subs)

// ---------------------------------------------------------------------------
// Bucket histogram: per-block LDS hist, then one global add per bucket
// ---------------------------------------------------------------------------
__global__ __launch_bounds__(256) void hist_bucket(const int* __restrict__ dst,
                                                   int* __restrict__ gcnt) {
    __shared__ int cnt[NB];
    for (int i = threadIdx.x; i < NB; i += 256) cnt[i] = 0;
    __syncthreads();
    int e0 = blockIdx.x * CHUNK;
    int e1 = min(e0 + CHUNK, N_EDGES);
    for (int e = e0 + threadIdx.x; e < e1; e += 256)
        atomicAdd(&cnt[dst[e] >> BSH], 1);
    __syncthreads();
    for (int i = threadIdx.x; i < NB; i += 256)
        if (cnt[i]) atomicAdd(&gcnt[i], cnt[i]);
}

// ---------------------------------------------------------------------------
// Exclusive scan over NB buckets (single 1024-thread block)
// ---------------------------------------------------------------------------
__global__ void scan_buckets(const int* __restrict__ gcnt,
                             int* __restrict__ off, int* __restrict__ cursor) {
    __shared__ int lds[1024];
    int t = threadIdx.x;
    int v = (t < NB) ? gcnt[t] : 0;
    int val = v;
    lds[t] = val; __syncthreads();
    for (int o = 1; o < 1024; o <<= 1) {
        int a = (t >= o) ? lds[t - o] : 0;
        __syncthreads();
        val += a; lds[t] = val;
        __syncthreads();
    }
    if (t < NB) { off[t] = val - v; cursor[t] = val - v; }
    if (t == 0) off[NB] = N_EDGES;
}

// ---------------------------------------------------------------------------
// Ranked fill into bucket-contiguous runs; packed = src | (dst&127)<<24
// ---------------------------------------------------------------------------
__global__ __launch_bounds__(256) void fill_bucket(const int* __restrict__ src,
                                                   const int* __restrict__ dst,
                                                   int* __restrict__ cursor,
                                                   unsigned* __restrict__ packed) {
    __shared__ int cnt[NB];
    __shared__ int base[NB];
    for (int i = threadIdx.x; i < NB; i += 256) cnt[i] = 0;
    __syncthreads();
    int e0 = blockIdx.x * CHUNK;
    int e1 = min(e0 + CHUNK, N_EDGES);
    for (int e = e0 + threadIdx.x; e < e1; e += 256)
        atomicAdd(&cnt[dst[e] >> BSH], 1);
    __syncthreads();
    for (int i = threadIdx.x; i < NB; i += 256) {
        int c = cnt[i];
        base[i] = c ? atomicAdd(&cursor[i], c) : 0;
        cnt[i] = 0;
    }
    __syncthreads();
    for (int e = e0 + threadIdx.x; e < e1; e += 256) {
        int d = dst[e];
        int b = d >> BSH;
        int lr = atomicAdd(&cnt[b], 1);
        packed[base[b] + lr] = (unsigned)src[e] | ((unsigned)(d & 127) << 24);
    }
}

// ---------------------------------------------------------------------------
// Per-bucket counting sort by local dst -> node-exact CSR (csr, rp)
// ---------------------------------------------------------------------------
__global__ __launch_bounds__(256) void sort_bucket(const unsigned* __restrict__ packed,
                                                   const int* __restrict__ off,
                                                   int* __restrict__ csr,
                                                   int* __restrict__ rp) {
    __shared__ unsigned ebuf[MAXB];
    __shared__ int cnt[256];
    __shared__ int cur[256];
    int b = blockIdx.x, t = threadIdx.x;
    int e0 = off[b], e1 = off[b + 1], m = e1 - e0;
    bool inl = (m <= MAXB);
    if (inl)
        for (int i = t; i < m; i += 256) ebuf[i] = packed[e0 + i];
    cnt[t] = 0;
    __syncthreads();
    for (int i = t; i < m; i += 256) {
        unsigned p = inl ? ebuf[i] : packed[e0 + i];
        atomicAdd(&cnt[p >> 24], 1);
    }
    __syncthreads();
    int v = cnt[t], val = v;
    cur[t] = val; __syncthreads();
    for (int o = 1; o < 256; o <<= 1) {
        int a = (t >= o) ? cur[t - o] : 0;
        __syncthreads();
        val += a; cur[t] = val;
        __syncthreads();
    }
    int excl = val - v;
    if (t < 128) {
        int node = b * 128 + t;
        if (node <= N_NODES) rp[node] = e0 + excl;   // last bucket writes rp[N] too
    }
    cur[t] = excl;
    __syncthreads();
    for (int i = t; i < m; i += 256) {
        unsigned p = inl ? ebuf[i] : packed[e0 + i];
        int l = p >> 24;
        int pos = atomicAdd(&cur[l], 1);
        csr[e0 + pos] = (int)(p & 0xFFFFFFu);
    }
}

// ---------------------------------------------------------------------------
// Gather (+fused prev-layer BN+ReLU on loads) + MLP + BN partials.
// 8 threads per node, register accumulation, 3-step butterfly merge,
// subs 0-3 compute 5 output channels each; partials stat-major.
// ---------------------------------------------------------------------------
template<int DIN, bool BN>
__global__ __launch_bounds__(256) void gather_mlp8(
        const float* __restrict__ h,
        const int* __restrict__ rp, const int* __restrict__ csr,
        const float* __restrict__ W,    // [DIN][HID]
        const float* __restrict__ bias,
        const float* __restrict__ ssin, // [2*HID] prev-layer scale/shift
        float* __restrict__ hpre,       // [N][HID]
        float* __restrict__ partials)   // [2*HID][NBG]
{
    __shared__ float sW[DIN * HID];
    __shared__ float sb[HID];
    __shared__ float sss[2 * HID];
    __shared__ float red[4][2 * HID];
    int t = threadIdx.x;
    for (int i = t; i < DIN * HID; i += 256) sW[i] = W[i];
    if (t < HID) sb[t] = bias[t];
    if constexpr (BN) { if (t < 2 * HID) sss[t] = ssin[t]; }
    __syncthreads();

    int node = blockIdx.x * 32 + (t >> 3);
    int sub  = t & 7;
    float u[DIN];
#pragma unroll
    for (int k = 0; k < DIN; k++) u[k] = 0.0f;

    if (node < N_NODES) {
        int e0 = rp[node], e1 = rp[node + 1];
        if (sub == 0) {   // self term (also BN+ReLU'd when BN)
            if constexpr (DIN == 20) {
                const float4* hv = (const float4*)(h + (size_t)node * 20);
#pragma unroll
                for (int q = 0; q < 5; q++) {
                    float4 a = hv[q];
                    float v0 = a.x, v1 = a.y, v2 = a.z, v3 = a.w;
                    if constexpr (BN) {
                        v0 = fmaxf(fmaf(v0, sss[4*q+0], sss[HID+4*q+0]), 0.f);
                        v1 = fmaxf(fmaf(v1, sss[4*q+1], sss[HID+4*q+1]), 0.f);
                        v2 = fmaxf(fmaf(v2, sss[4*q+2], sss[HID+4*q+2]), 0.f);
                        v3 = fmaxf(fmaf(v3, sss[4*q+3], sss[HID+4*q+3]), 0.f);
                    }
                    u[4*q] += v0; u[4*q+1] += v1; u[4*q+2] += v2; u[4*q+3] += v3;
                }
            } else {
                const float2* hv = (const float2*)(h + (size_t)node * DIN);
#pragma unroll
                for (int q = 0; q < 5; q++) {
                    float2 a = hv[q];
                    u[2*q] += a.x; u[2*q+1] += a.y;
                }
            }
        }
        int e = e0 + sub;
        // pair-unrolled: two rows in flight per iteration
        for (; e + 8 < e1; e += 16) {
            int s0 = csr[e], s1 = csr[e + 8];
            if constexpr (DIN == 20) {
                const float4* a0 = (const float4*)(h + (size_t)s0 * 20);
                const float4* a1 = (const float4*)(h + (size_t)s1 * 20);
#pragma unroll
                for (int q = 0; q < 5; q++) {
                    float4 x0 = a0[q], x1 = a1[q];
                    if constexpr (BN) {
                        x0.x = fmaxf(fmaf(x0.x, sss[4*q+0], sss[HID+4*q+0]), 0.f);
                        x0.y = fmaxf(fmaf(x0.y, sss[4*q+1], sss[HID+4*q+1]), 0.f);
                        x0.z = fmaxf(fmaf(x0.z, sss[4*q+2], sss[HID+4*q+2]), 0.f);
                        x0.w = fmaxf(fmaf(x0.w, sss[4*q+3], sss[HID+4*q+3]), 0.f);
                        x1.x = fmaxf(fmaf(x1.x, sss[4*q+0], sss[HID+4*q+0]), 0.f);
                        x1.y = fmaxf(fmaf(x1.y, sss[4*q+1], sss[HID+4*q+1]), 0.f);
                        x1.z = fmaxf(fmaf(x1.z, sss[4*q+2], sss[HID+4*q+2]), 0.f);
                        x1.w = fmaxf(fmaf(x1.w, sss[4*q+3], sss[HID+4*q+3]), 0.f);
                    }
                    u[4*q]   += x0.x + x1.x;
                    u[4*q+1] += x0.y + x1.y;
                    u[4*q+2] += x0.z + x1.z;
                    u[4*q+3] += x0.w + x1.w;
                }
            } else {
                const float2* a0 = (const float2*)(h + (size_t)s0 * DIN);
                const float2* a1 = (const float2*)(h + (size_t)s1 * DIN);
#pragma unroll
                for (int q = 0; q < 5; q++) {
                    float2 x0 = a0[q], x1 = a1[q];
                    u[2*q]   += x0.x + x1.x;
                    u[2*q+1] += x0.y + x1.y;
                }
            }
        }
        for (; e < e1; e += 8) {
            int s0 = csr[e];
            if constexpr (DIN == 20) {
                const float4* a0 = (const float4*)(h + (size_t)s0 * 20);
#pragma unroll
                for (int q = 0; q < 5; q++) {
                    float4 x0 = a0[q];
                    if constexpr (BN) {
                        x0.x = fmaxf(fmaf(x0.x, sss[4*q+0], sss[HID+4*q+0]), 0.f);
                        x0.y = fmaxf(fmaf(x0.y, sss[4*q+1], sss[HID+4*q+1]), 0.f);
                        x0.z = fmaxf(fmaf(x0.z, sss[4*q+2], sss[HID+4*q+2]), 0.f);
                        x0.w = fmaxf(fmaf(x0.w, sss[4*q+3], sss[HID+4*q+3]), 0.f);
                    }
                    u[4*q] += x0.x; u[4*q+1] += x0.y; u[4*q+2] += x0.z; u[4*q+3] += x0.w;
                }
            } else {
                const float2* a0 = (const float2*)(h + (size_t)s0 * DIN);
#pragma unroll
                for (int q = 0; q < 5; q++) {
                    float2 x0 = a0[q];
                    u[2*q] += x0.x; u[2*q+1] += x0.y;
                }
            }
        }
    }

    // merge 8 sub-accumulators (all 8 lanes end with full sum)
#pragma unroll
    for (int k = 0; k < DIN; k++) {
        u[k] += __shfl_xor(u[k], 1);
        u[k] += __shfl_xor(u[k], 2);
        u[k] += __shfl_xor(u[k], 4);
    }

    // MLP: subs 0-3 compute channels [sub*5, sub*5+5); subs 4-7 duplicate (masked)
    const int c0 = (sub & 3) * 5;
    float out[5];
#pragma unroll
    for (int j = 0; j < 5; j++) out[j] = sb[c0 + j];
#pragma unroll
    for (int k = 0; k < DIN; k++) {
        float uk = u[k];
#pragma unroll
        for (int j = 0; j < 5; j++)
            out[j] = fmaf(uk, sW[k * HID + c0 + j], out[j]);
    }
    bool live = (node < N_NODES) && (sub < 4);
    if (live) {
        float* op = hpre + (size_t)node * HID + c0;
#pragma unroll
        for (int j = 0; j < 5; j++) op[j] = out[j];
    }

    // BN partials: mask dup/out-of-range, reduce over the 8 nodes of the wave
    float msk = live ? 1.0f : 0.0f;
    float s1[5], s2[5];
#pragma unroll
    for (int j = 0; j < 5; j++) {
        float o = out[j] * msk;
        s1[j] = o; s2[j] = o * out[j];
    }
    for (int o = 8; o < 64; o <<= 1) {
#pragma unroll
        for (int j = 0; j < 5; j++) {
            s1[j] += __shfl_down(s1[j], o);
            s2[j] += __shfl_down(s2[j], o);
        }
    }
    int lane = t & 63, wave = t >> 6;
    if (lane < 4) {
#pragma unroll
        for (int j = 0; j < 5; j++) {
            red[wave][lane * 5 + j]       = s1[j];
            red[wave][HID + lane * 5 + j] = s2[j];
        }
    }
    __syncthreads();
    if (t < 2 * HID)
        partials[(size_t)t * NBG + blockIdx.x] =
            red[0][t] + red[1][t] + red[2][t] + red[3][t];
}

// ---------------------------------------------------------------------------
// BN prep: 20 blocks, block c reduces stat rows c and c+20 (coalesced), f64
// ---------------------------------------------------------------------------
__global__ __launch_bounds__(256) void bn_prep(const float* __restrict__ partials,
                                               const float* __restrict__ g,
                                               const float* __restrict__ beta,
                                               float* __restrict__ ss) {
    int c = blockIdx.x, t = threadIdx.x;
    double a1 = 0.0, a2 = 0.0;
    for (int i = t; i < NBG; i += 256) {
        a1 += (double)partials[(size_t)c * NBG + i];
        a2 += (double)partials[(size_t)(c + HID) * NBG + i];
    }
    for (int o = 32; o; o >>= 1) {
        a1 += __shfl_down(a1, o);
        a2 += __shfl_down(a2, o);
    }
    __shared__ double r1[4], r2[4];
    int lane = t & 63, wave = t >> 6;
    if (lane == 0) { r1[wave] = a1; r2[wave] = a2; }
    __syncthreads();
    if (t == 0) {
        double su = r1[0] + r1[1] + r1[2] + r1[3];
        double sq = r2[0] + r2[1] + r2[2] + r2[3];
        double mu  = su / (double)N_NODES;
        double var = sq / (double)N_NODES - mu * mu;
        float sc = g[c] * (float)(1.0 / sqrt(var + (double)BN_EPS));
        ss[c]       = sc;
        ss[HID + c] = beta[c] - (float)mu * sc;
    }
}

// ---------------------------------------------------------------------------
// graph_ptr from sorted batch (handles empty graphs)
// ---------------------------------------------------------------------------
__global__ void gptr_kernel(const int* __restrict__ batch, int* __restrict__ gptr) {
    int n = blockIdx.x * blockDim.x + threadIdx.x;
    if (n >= N_NODES) return;
    int g = batch[n];
    int gp = (n == 0) ? -1 : batch[n - 1];
    for (int q = gp + 1; q <= g; q++) gptr[q] = n;
    if (n == N_NODES - 1)
        for (int q = g + 1; q <= N_GRAPHS; q++) gptr[q] = N_NODES;
}

// ---------------------------------------------------------------------------
// Pool (+fused BN3+ReLU) + FC, block per graph
// ---------------------------------------------------------------------------
__global__ __launch_bounds__(256) void pool_fc(const float* __restrict__ h,
                                               const int* __restrict__ gptr,
                                               const float* __restrict__ ss,
                                               const float* __restrict__ fcW,
                                               const float* __restrict__ fcb,
                                               float* __restrict__ out) {
    __shared__ float red[12][HID];
    __shared__ float sss[2 * HID];
    __shared__ float pl[HID];
    int g = blockIdx.x, t = threadIdx.x;
    if (t < 2 * HID) sss[t] = ss[t];
    __syncthreads();
    int n0 = gptr[g], n1 = gptr[g + 1];
    if (t < 240) {
        int c = t % HID, grp = t / HID;
        float s = 0.0f;
        for (int n = n0 + grp; n < n1; n += 12) {
            float v = fmaf(h[(size_t)n * HID + c], sss[c], sss[HID + c]);
            s += v > 0.0f ? v : 0.0f;
        }
        red[grp][c] = s;
    }
    __syncthreads();
    if (t < HID) {
        float a = 0.0f;
#pragma unroll
        for (int q = 0; q < 12; q++) a += red[q][t];
        pl[t] = a;
    }
    __syncthreads();
    if (t < 2) {
        float o = fcb[t];
#pragma unroll
        for (int k = 0; k < HID; k++) o = fmaf(pl[k], fcW[k * 2 + t], o);
        out[g * 2 + t] = o;
    }
}

extern "C" void kernel_launch(void* const* d_in, const int* in_sizes, int n_in,
                              void* d_out, int out_size, void* d_ws, size_t ws_size,
                              hipStream_t stream) {
    const float* x     = (const float*)d_in[0];
    const int*   eidx  = (const int*)d_in[1];
    const int*   batch = (const int*)d_in[2];
    const float* W1 = (const float*)d_in[3];
    const float* b1 = (const float*)d_in[4];
    const float* g1 = (const float*)d_in[5];
    const float* be1 = (const float*)d_in[6];
    const float* W2 = (const float*)d_in[7];
    const float* b2 = (const float*)d_in[8];
    const float* g2 = (const float*)d_in[9];
    const float* be2 = (const float*)d_in[10];
    const float* W3 = (const float*)d_in[11];
    const float* b3 = (const float*)d_in[12];
    const float* g3 = (const float*)d_in[13];
    const float* be3 = (const float*)d_in[14];
    const float* fcW = (const float*)d_in[15];
    const float* fcb = (const float*)d_in[16];
    float* out = (float*)d_out;

    const int* src = eidx;
    const int* dst = eidx + N_EDGES;

    // workspace layout (bytes). packed (build-only) aliases hA/hB: the build
    // (hist/scan/fill/sort) completes before any gather writes hA/hB.
    char* ws = (char*)d_ws;
    float* hA      = (float*)(ws + 0);               // 8,000,000
    float* hB      = (float*)(ws + 8000000);         // 8,000,000
    unsigned* packed = (unsigned*)(ws + 0);          // 12,800,000 (temp alias)
    int*   csr     = (int*)(ws + 16000000);          // 12,800,000
    int*   rp      = (int*)(ws + 28800000);          // 400,004
    int*   off     = (int*)(ws + 29200128);          // 3,132
    int*   cursor  = (int*)(ws + 29203328);          // 3,128
    int*   gcnt    = (int*)(ws + 29206528);          // 3,128
    float* partials= (float*)(ws + 29209728);        // 40*3125*4 = 500,000
    float* ss1     = (float*)(ws + 29709728);        // 160
    float* ss2     = (float*)(ws + 29709888);        // 160
    float* ss3     = (float*)(ws + 29710048);        // 160
    int*   gptr    = (int*)(ws + 29710208);          // 4,004

    const int BLK = 256;

    // ---- sorted node-exact CSR (built once, reused by all 3 layers) ----
    hipMemsetAsync(gcnt, 0, NB * sizeof(int), stream);
    hist_bucket<<<FILL_BLOCKS, BLK, 0, stream>>>(dst, gcnt);
    scan_buckets<<<1, 1024, 0, stream>>>(gcnt, off, cursor);
    fill_bucket<<<FILL_BLOCKS, BLK, 0, stream>>>(src, dst, cursor, packed);
    sort_bucket<<<NB, BLK, 0, stream>>>(packed, off, csr, rp);
    gptr_kernel<<<(N_NODES + BLK - 1) / BLK, BLK, 0, stream>>>(batch, gptr);

    // ---- layer 1 (DIN=10, no input BN) ----
    gather_mlp8<IN_DIM, false><<<NBG, BLK, 0, stream>>>(x, rp, csr, W1, b1, ss1, hA, partials);
    bn_prep<<<HID, BLK, 0, stream>>>(partials, g1, be1, ss1);

    // ---- layer 2 (DIN=20, fused BN1+ReLU on loads) ----
    gather_mlp8<HID, true><<<NBG, BLK, 0, stream>>>(hA, rp, csr, W2, b2, ss1, hB, partials);
    bn_prep<<<HID, BLK, 0, stream>>>(partials, g2, be2, ss2);

    // ---- layer 3 (DIN=20, fused BN2+ReLU on loads) ----
    gather_mlp8<HID, true><<<NBG, BLK, 0, stream>>>(hB, rp, csr, W3, b3, ss2, hA, partials);
    bn_prep<<<HID, BLK, 0, stream>>>(partials, g3, be3, ss3);

    // ---- pool (+BN3+ReLU) + FC ----
    pool_fc<<<N_GRAPHS, BLK, 0, stream>>>(hA, gptr, ss3, fcW, fcb, out);
}